// Round 3
// baseline (679.377 us; speedup 1.0000x reference)
//
#include <hip/hip_runtime.h>
#include <math.h>

#define NB 1024
#define NF 36
#define ED 256
#define NK 8
#define NN2 1296   // 36*36
#define QPK 162    // 1296/8
#define XR 48      // padded X rows per batch (3 tiles of 16)

typedef _Float16 f16;
typedef f16 f16x8 __attribute__((ext_vector_type(8)));
typedef float f32x4 __attribute__((ext_vector_type(4)));

#define WXSTR 136   // f16 per Wx half-row (128 + 8 pad)

__device__ __forceinline__ f32x4 mfma16(f16x8 a, f16x8 b, f32x4 c) {
    return __builtin_amdgcn_mfma_f32_16x16x32_f16(a, b, c, 0, 0, 0);
}

// ---- pack W[k][c][d] -> B-fragment order, scaled by 16 (keeps W-lo normal) ----
__global__ __launch_bounds__(256) void prep_w(const float* __restrict__ W,
                                              f16x8* __restrict__ WfH,
                                              f16x8* __restrict__ WfL) {
    int idx = blockIdx.x * 256 + threadIdx.x;   // 65536 total
    int dox = idx & 31;
    int c   = (idx >> 5) & 255;
    int k   = idx >> 13;
    const float* src = W + ((size_t)(k * 256 + c)) * 256 + dox * 8;
    float4 a = *(const float4*)src;
    float4 b = *(const float4*)(src + 4);
    float v[8] = {a.x, a.y, a.z, a.w, b.x, b.y, b.z, b.w};
    f16x8 hi, lo;
    #pragma unroll
    for (int j = 0; j < 8; ++j) {
        float sv = v[j] * 16.0f;
        f16 h = (f16)sv;
        hi[j] = h;
        lo[j] = (f16)(sv - (float)h);
    }
    int kc = dox >> 2, qd = dox & 3, ct = c >> 4;
    int fr = ((k * 16 + ct) * 8 + kc) * 64 + qd * 16 + (c & 15);
    WfH[fr] = hi;
    WfL[fr] = lo;
}

// ---- split X -> Xh/Xl (f16, rows padded to 48 with zeros) + v1/v2 for all k ----
__global__ __launch_bounds__(256) void prep_x(const float* __restrict__ texts,
                                              f16* __restrict__ XhG, f16* __restrict__ XlG,
                                              const float* __restrict__ V1w, const float* __restrict__ V1b,
                                              const float* __restrict__ V2w, const float* __restrict__ V2b,
                                              float* __restrict__ v12) {
    __shared__ float Xs[NF * 260];   // stride 260: banks spread for the dot phase
    const int b = blockIdx.x;
    const int t = threadIdx.x;
    const float* xb = texts + (size_t)b * NF * ED;
    f16* xh = XhG + (size_t)b * XR * ED;
    f16* xl = XlG + (size_t)b * XR * ED;

    for (int i = t; i < NF * 128; i += 256) {
        int row = i >> 7, c2 = (i & 127) << 1;
        float v0 = xb[row * ED + c2];
        float v1 = xb[row * ED + c2 + 1];
        Xs[row * 260 + c2]     = v0;
        Xs[row * 260 + c2 + 1] = v1;
        union { f16 h[2]; unsigned u; } ph, pl;
        f16 h0 = (f16)v0, h1 = (f16)v1;
        ph.h[0] = h0; ph.h[1] = h1;
        pl.h[0] = (f16)(v0 - (float)h0); pl.h[1] = (f16)(v1 - (float)h1);
        *(unsigned*)(xh + row * ED + c2) = ph.u;
        *(unsigned*)(xl + row * ED + c2) = pl.u;
    }
    for (int i = t; i < (XR - NF) * 128; i += 256) {
        int row = NF + (i >> 7), c2 = (i & 127) << 1;
        *(unsigned*)(xh + row * ED + c2) = 0u;
        *(unsigned*)(xl + row * ED + c2) = 0u;
    }
    __syncthreads();
    // v12[b][k][which][n] = (which ? V2w[k] : V1w[k]) . X[n] + bias
    for (int tv = t; tv < NK * 2 * NF; tv += 256) {
        int k = tv / (2 * NF), rem = tv % (2 * NF);
        int which = rem / NF, n = rem % NF;
        const float4* wp = (const float4*)((which ? V2w : V1w) + k * ED);
        const float4* xr = (const float4*)(&Xs[n * 260]);
        float s = 0.f;
        #pragma unroll 8
        for (int d4 = 0; d4 < 64; ++d4) {
            float4 a = wp[d4], x = xr[d4];
            s += a.x * x.x + a.y * x.y + a.z * x.z + a.w * x.w;
        }
        v12[(size_t)b * (NK * 2 * NF) + tv] = s + (which ? V2b[k] : V1b[k]);
    }
}

__global__ __launch_bounds__(256, 4) void ntn_main(
    const f16* __restrict__ XhG, const f16* __restrict__ XlG,
    const f16x8* __restrict__ WfH, const f16x8* __restrict__ WfL,
    const float* __restrict__ Wb, const float* __restrict__ v12,
    const float* __restrict__ Uw, const float* __restrict__ Ubp,
    float* __restrict__ logits)
{
    __shared__ f16 Wxh[XR * WXSTR];   // 13056 B
    __shared__ f16 Wxl[XR * WXSTR];   // 13056 B
    __shared__ float v1s[NF], v2s[NF], Uws[9];

    const int k    = blockIdx.x;
    const int b    = blockIdx.y;
    const int t    = threadIdx.x;
    const int wave = t >> 6;
    const int lane = t & 63;
    const int quad = lane >> 4;
    const int l15  = lane & 15;

    const f16* Xh = XhG + (size_t)b * XR * ED;
    const f16* Xl = XlG + (size_t)b * XR * ED;
    const f16x8* WfHk = WfH + (size_t)k * 16 * 8 * 64;
    const f16x8* WfLk = WfL + (size_t)k * 16 * 8 * 64;

    if (t < 2 * NF) {
        float v = v12[(size_t)b * (NK * 2 * NF) + k * (2 * NF) + t];
        if (t < NF) v1s[t] = v; else v2s[t - NF] = v;
    }
    if (t < 8) Uws[t] = Uw[t];
    if (t == 8) Uws[8] = Ubp[0];

    // Wb values for both halves (c = (h*8 + wave (+4))*16 + l15)
    float wbv[2][2];
    #pragma unroll
    for (int h = 0; h < 2; ++h) {
        wbv[h][0] = Wb[k * ED + (h * 8 + wave) * 16 + l15];
        wbv[h][1] = Wb[k * ED + (h * 8 + wave + 4) * 16 + l15];
    }

    f32x4 sacc[3];
    #pragma unroll
    for (int i = 0; i < 3; ++i) sacc[i] = (f32x4){0.f, 0.f, 0.f, 0.f};

    // per-rt A-frag base pointers (offset kc*32 halfwords folds to imm)
    const f16* pa_h[3]; const f16* pa_l[3];
    #pragma unroll
    for (int rt = 0; rt < 3; ++rt) {
        int off = (rt * 16 + l15) * ED + quad * 8;
        pa_h[rt] = Xh + off;
        pa_l[rt] = Xl + off;
    }

    for (int h = 0; h < 2; ++h) {
        // ===== phase 1: Wx[:, half h] = X * W[k]^T (AhBh + AhBl + AlBh) =====
        f32x4 acc[3][2];
        #pragma unroll
        for (int i = 0; i < 3; ++i) { acc[i][0] = (f32x4){0,0,0,0}; acc[i][1] = (f32x4){0,0,0,0}; }
        const int ct0 = h * 8 + wave;
        const int ct1 = ct0 + 4;
        #pragma unroll 2
        for (int kc = 0; kc < 8; ++kc) {
            f16x8 ah[3], al[3];
            #pragma unroll
            for (int rt = 0; rt < 3; ++rt) {
                ah[rt] = *(const f16x8*)(pa_h[rt] + kc * 32);
                al[rt] = *(const f16x8*)(pa_l[rt] + kc * 32);
            }
            f16x8 bh0 = WfHk[(ct0 * 8 + kc) * 64 + lane];
            f16x8 bl0 = WfLk[(ct0 * 8 + kc) * 64 + lane];
            f16x8 bh1 = WfHk[(ct1 * 8 + kc) * 64 + lane];
            f16x8 bl1 = WfLk[(ct1 * 8 + kc) * 64 + lane];
            #pragma unroll
            for (int rt = 0; rt < 3; ++rt) {
                acc[rt][0] = mfma16(ah[rt], bh0, acc[rt][0]);
                acc[rt][0] = mfma16(ah[rt], bl0, acc[rt][0]);
                acc[rt][0] = mfma16(al[rt], bh0, acc[rt][0]);
                acc[rt][1] = mfma16(ah[rt], bh1, acc[rt][1]);
                acc[rt][1] = mfma16(ah[rt], bl1, acc[rt][1]);
                acc[rt][1] = mfma16(al[rt], bh1, acc[rt][1]);
            }
        }
        __syncthreads();   // prior phase-2 reads of Wx done before overwrite
        // ---- unscale (W was *16), add bias, split -> LDS ----
        #pragma unroll
        for (int rt = 0; rt < 3; ++rt) {
            #pragma unroll
            for (int j2 = 0; j2 < 2; ++j2) {
                const float wb = wbv[h][j2];
                const int cl = (j2 ? (wave + 4) : wave) * 16 + l15;
                #pragma unroll
                for (int r = 0; r < 4; ++r) {
                    const int row = rt * 16 + quad * 4 + r;
                    float v = acc[rt][j2][r] * 0.0625f + wb;
                    f16 hh = (f16)v;
                    Wxh[row * WXSTR + cl] = hh;
                    Wxl[row * WXSTR + cl] = (f16)(v - (float)hh);
                }
            }
        }
        __syncthreads();
        // ===== phase 2: S += Wx[:, half] * X[:, half]^T =====
        for (int p = wave; p < 9; p += 4) {
            const int nt = p / 3, mt = p % 3;
            const int i = p >> 2;
            const f16* wxh_p = Wxh + (nt * 16 + l15) * WXSTR + quad * 8;
            const f16* wxl_p = Wxl + (nt * 16 + l15) * WXSTR + quad * 8;
            const f16* xbh_p = Xh + (mt * 16 + l15) * ED + h * 128 + quad * 8;
            const f16* xbl_p = Xl + (mt * 16 + l15) * ED + h * 128 + quad * 8;
            #pragma unroll
            for (int kc2 = 0; kc2 < 4; ++kc2) {
                f16x8 pah = *(const f16x8*)(wxh_p + kc2 * 32);
                f16x8 pal = *(const f16x8*)(wxl_p + kc2 * 32);
                f16x8 pbh = *(const f16x8*)(xbh_p + kc2 * 32);
                f16x8 pbl = *(const f16x8*)(xbl_p + kc2 * 32);
                sacc[i] = mfma16(pah, pbh, sacc[i]);
                sacc[i] = mfma16(pah, pbl, sacc[i]);
                sacc[i] = mfma16(pal, pbh, sacc[i]);
            }
        }
    }

    // ===== epilogue: T = tanh(S + v1 + v2) -> Ts (overlays Wxh), U-dot =====
    __syncthreads();
    float* Ts = (float*)Wxh;   // 1296 floats = 5184 B <= 13056 B
    for (int p = wave; p < 9; p += 4) {
        const int nt = p / 3, mt = p % 3;
        const int i = p >> 2;
        const int m = mt * 16 + l15;
        if (m < NF) {
            #pragma unroll
            for (int r = 0; r < 4; ++r) {
                const int n = nt * 16 + quad * 4 + r;
                if (n < NF) {
                    float sv = sacc[i][r] + v1s[n] + v2s[m];
                    float e = __expf(2.f * sv);
                    Ts[n * NF + m] = 1.f - 2.f / (e + 1.f);
                }
            }
        }
    }
    __syncthreads();
    if (t < QPK) {
        const float* tp = Ts + t * 8;
        float lg = Uws[8];
        #pragma unroll
        for (int j = 0; j < 8; ++j) lg += Uws[j] * tp[j];
        logits[(size_t)b * NN2 + k * QPK + t] = lg;
    }
}

// ---- in-place row softmax: 4 rows per 256-thread block (one per wave) ----
__global__ __launch_bounds__(256) void softmax_rows(float* __restrict__ out) {
    int row = blockIdx.x * 4 + (threadIdx.x >> 6);
    int t = threadIdx.x & 63;
    float* p = out + (size_t)row * NF;
    float v = (t < NF) ? p[t] : -INFINITY;
    float mx = v;
    #pragma unroll
    for (int off = 32; off > 0; off >>= 1) mx = fmaxf(mx, __shfl_xor(mx, off));
    float e = (t < NF) ? __expf(v - mx) : 0.f;
    float sm = e;
    #pragma unroll
    for (int off = 32; off > 0; off >>= 1) sm += __shfl_xor(sm, off);
    if (t < NF) p[t] = e / sm;
}

extern "C" void kernel_launch(void* const* d_in, const int* in_sizes, int n_in,
                              void* d_out, int out_size, void* d_ws, size_t ws_size,
                              hipStream_t stream) {
    const float* texts = (const float*)d_in[0];
    const float* W     = (const float*)d_in[1];
    const float* Wb    = (const float*)d_in[2];
    const float* V1w   = (const float*)d_in[3];
    const float* V1b   = (const float*)d_in[4];
    const float* V2w   = (const float*)d_in[5];
    const float* V2b   = (const float*)d_in[6];
    const float* Uw    = (const float*)d_in[7];
    const float* Ub    = (const float*)d_in[8];

    char* ws = (char*)d_ws;
    f16x8* WfH = (f16x8*)ws;                          //  1 MiB
    f16x8* WfL = (f16x8*)(ws + (1 << 20));            //  1 MiB
    f16*   XhG = (f16*)(ws + (2 << 20));              // 24 MiB (1024 * 48*256 * 2B)
    f16*   XlG = (f16*)(ws + (2 << 20) + (size_t)NB * XR * ED * 2);   // 24 MiB
    float* v12 = (float*)(ws + (2 << 20) + (size_t)2 * NB * XR * ED * 2); // 2.25 MiB
    float* logits = (float*)d_out;

    prep_w<<<256, 256, 0, stream>>>(W, WfH, WfL);
    prep_x<<<NB, 256, 0, stream>>>(texts, XhG, XlG, V1w, V1b, V2w, V2b, v12);
    ntn_main<<<dim3(NK, NB), 256, 0, stream>>>(XhG, XlG, WfH, WfL, Wb, v12, Uw, Ub, logits);
    softmax_rows<<<NB * NF / 4, 256, 0, stream>>>(logits);
}

// Round 4
// 325.063 us; speedup vs baseline: 2.0900x; 2.0900x over previous
//
#include <hip/hip_runtime.h>
#include <math.h>

#define NB 1024
#define NF 36
#define ED 256
#define NK 8
#define NN2 1296   // 36*36
#define QPK 162    // 1296/8

typedef _Float16 f16;
typedef f16 f16x8 __attribute__((ext_vector_type(8)));
typedef float f32x4 __attribute__((ext_vector_type(4)));

#define WXSTR 136     // f16 per Wx half-row (128 + 8 pad); 272B = 17*16 (b128-aligned)
#define NFRAG 1536    // 3 row-tiles * 8 kc * 64 lanes, f16x8 each, per hi/lo component

// LDS layout (dynamic): Xh 24576 | Xl 24576 | Wxh 13056 | Wxl 13056 | v1s/v2s/Uws
#define XH_OFF  0
#define XL_OFF  24576
#define WXH_OFF 49152
#define WXL_OFF 62208
#define V_OFF   75264
#define SMEM_BYTES (V_OFF + (NF + NF + 9) * 4)   // 75588

__device__ __forceinline__ f32x4 mfma16(f16x8 a, f16x8 b, f32x4 c) {
    return __builtin_amdgcn_mfma_f32_16x16x32_f16(a, b, c, 0, 0, 0);
}

// ---- pack W[k][c][d] -> B-fragment order, scaled by 16 (keeps W-lo fp16-normal) ----
__global__ __launch_bounds__(256) void prep_w(const float* __restrict__ W,
                                              f16x8* __restrict__ WfH,
                                              f16x8* __restrict__ WfL) {
    int idx = blockIdx.x * 256 + threadIdx.x;   // 65536 total
    int dox = idx & 31;
    int c   = (idx >> 5) & 255;
    int k   = idx >> 13;
    const float* src = W + ((size_t)(k * 256 + c)) * 256 + dox * 8;
    float4 a = *(const float4*)src;
    float4 b = *(const float4*)(src + 4);
    float v[8] = {a.x, a.y, a.z, a.w, b.x, b.y, b.z, b.w};
    f16x8 hi, lo;
    #pragma unroll
    for (int j = 0; j < 8; ++j) {
        float sv = v[j] * 16.0f;
        f16 h = (f16)sv;
        hi[j] = h;
        lo[j] = (f16)(sv - (float)h);
    }
    int kc = dox >> 2, qd = dox & 3, ct = c >> 4;
    int fr = ((k * 16 + ct) * 8 + kc) * 64 + qd * 16 + (c & 15);
    WfH[fr] = hi;
    WfL[fr] = lo;
}

// ---- split X into hi/lo f16 *fragment-order* arrays + v1/v2 for all k ----
// XfH[b][ (rt*8+kc)*64 + lane ] : lane=q*16+l15 holds X[rt*16+l15][kc*32+q*8 .. +7]
__global__ __launch_bounds__(256) void prep_x(const float* __restrict__ texts,
                                              f16x8* __restrict__ XfH, f16x8* __restrict__ XfL,
                                              const float* __restrict__ V1w, const float* __restrict__ V1b,
                                              const float* __restrict__ V2w, const float* __restrict__ V2b,
                                              float* __restrict__ v12) {
    __shared__ float Xs[NF * 260];
    const int b = blockIdx.x;
    const int t = threadIdx.x;
    const float* xb = texts + (size_t)b * NF * ED;

    for (int i = t; i < NF * 64; i += 256) {
        int row = i >> 6, c4 = (i & 63) << 2;
        *(float4*)(&Xs[row * 260 + c4]) = *(const float4*)(xb + row * ED + c4);
    }
    __syncthreads();

    for (int i = t; i < NFRAG; i += 256) {
        int rt = i >> 9, kc = (i >> 6) & 7, lane = i & 63;
        int q = lane >> 4, l15 = lane & 15;
        int row = rt * 16 + l15;
        int d0 = kc * 32 + q * 8;
        f16x8 hi, lo;
        if (row < NF) {
            const float* s = &Xs[row * 260 + d0];
            #pragma unroll
            for (int j = 0; j < 8; ++j) {
                float v = s[j];
                f16 h = (f16)v;
                hi[j] = h;
                lo[j] = (f16)(v - (float)h);
            }
        } else {
            #pragma unroll
            for (int j = 0; j < 8; ++j) { hi[j] = (f16)0.f; lo[j] = (f16)0.f; }
        }
        XfH[(size_t)b * NFRAG + i] = hi;
        XfL[(size_t)b * NFRAG + i] = lo;
    }

    // v12[b][k][which][n]
    for (int tv = t; tv < NK * 2 * NF; tv += 256) {
        int k = tv / (2 * NF), rem = tv % (2 * NF);
        int which = rem / NF, n = rem % NF;
        const float4* wp = (const float4*)((which ? V2w : V1w) + k * ED);
        const float4* xr = (const float4*)(&Xs[n * 260]);
        float s = 0.f;
        #pragma unroll 8
        for (int d4 = 0; d4 < 64; ++d4) {
            float4 a = wp[d4], x = xr[d4];
            s += a.x * x.x + a.y * x.y + a.z * x.z + a.w * x.w;
        }
        v12[(size_t)b * (NK * 2 * NF) + tv] = s + (which ? V2b[k] : V1b[k]);
    }
}

__global__ __launch_bounds__(256, 2) void ntn_main(
    const f16x8* __restrict__ XfHG, const f16x8* __restrict__ XfLG,
    const f16x8* __restrict__ WfH, const f16x8* __restrict__ WfL,
    const float* __restrict__ Wb, const float* __restrict__ v12,
    const float* __restrict__ Uw, const float* __restrict__ Ubp,
    float* __restrict__ logits)
{
    extern __shared__ char smem[];
    f16x8* Xh  = (f16x8*)(smem + XH_OFF);
    f16x8* Xl  = (f16x8*)(smem + XL_OFF);
    f16*   Wxh = (f16*)(smem + WXH_OFF);
    f16*   Wxl = (f16*)(smem + WXL_OFF);
    float* v1s = (float*)(smem + V_OFF);
    float* v2s = v1s + NF;
    float* Uws = v2s + NF;

    // XCD swizzle: id = (b>>3)*64 + k*8 + (b&7)  ->  all 8 k's of a b share id%8 (same XCD)
    const int id  = blockIdx.x;
    const int rem = id >> 3;
    const int k   = rem & 7;
    const int b   = ((rem >> 3) << 3) | (id & 7);

    const int t    = threadIdx.x;
    const int wave = t >> 6;
    const int lane = t & 63;
    const int quad = lane >> 4;
    const int l15  = lane & 15;

    // ---- stage X fragments into LDS (coalesced dwordx4) ----
    {
        const f16x8* gh = XfHG + (size_t)b * NFRAG;
        const f16x8* gl = XfLG + (size_t)b * NFRAG;
        #pragma unroll
        for (int i = 0; i < 6; ++i) Xh[t + i * 256] = gh[t + i * 256];
        #pragma unroll
        for (int i = 0; i < 6; ++i) Xl[t + i * 256] = gl[t + i * 256];
    }
    if (t < 2 * NF) {
        float v = v12[(size_t)b * (NK * 2 * NF) + k * (2 * NF) + t];
        if (t < NF) v1s[t] = v; else v2s[t - NF] = v;
    }
    if (t < 8) Uws[t] = Uw[t];
    if (t == 8) Uws[8] = Ubp[0];

    float wbv[2][2];
    #pragma unroll
    for (int h = 0; h < 2; ++h) {
        wbv[h][0] = Wb[k * ED + (h * 8 + wave) * 16 + l15];
        wbv[h][1] = Wb[k * ED + (h * 8 + wave + 4) * 16 + l15];
    }
    __syncthreads();

    const f16x8* WfHk = WfH + (size_t)k * 16 * 8 * 64;
    const f16x8* WfLk = WfL + (size_t)k * 16 * 8 * 64;

    f32x4 sacc[3];
    #pragma unroll
    for (int i = 0; i < 3; ++i) sacc[i] = (f32x4){0.f, 0.f, 0.f, 0.f};

    for (int h = 0; h < 2; ++h) {
        // ===== phase 1: Wx[:, half h] = X * W[k]^T (AhBh + AhBl + AlBh) =====
        f32x4 acc[3][2];
        #pragma unroll
        for (int i = 0; i < 3; ++i) { acc[i][0] = (f32x4){0,0,0,0}; acc[i][1] = (f32x4){0,0,0,0}; }
        const int ct0 = h * 8 + wave;
        const int ct1 = ct0 + 4;
        #pragma unroll 2
        for (int kc = 0; kc < 8; ++kc) {
            f16x8 ah[3], al[3];
            #pragma unroll
            for (int rt = 0; rt < 3; ++rt) {
                ah[rt] = Xh[(rt * 8 + kc) * 64 + lane];   // conflict-free ds_read_b128
                al[rt] = Xl[(rt * 8 + kc) * 64 + lane];
            }
            f16x8 bh0 = WfHk[(ct0 * 8 + kc) * 64 + lane];
            f16x8 bl0 = WfLk[(ct0 * 8 + kc) * 64 + lane];
            f16x8 bh1 = WfHk[(ct1 * 8 + kc) * 64 + lane];
            f16x8 bl1 = WfLk[(ct1 * 8 + kc) * 64 + lane];
            #pragma unroll
            for (int rt = 0; rt < 3; ++rt) {
                acc[rt][0] = mfma16(ah[rt], bh0, acc[rt][0]);
                acc[rt][0] = mfma16(ah[rt], bl0, acc[rt][0]);
                acc[rt][0] = mfma16(al[rt], bh0, acc[rt][0]);
                acc[rt][1] = mfma16(ah[rt], bh1, acc[rt][1]);
                acc[rt][1] = mfma16(ah[rt], bl1, acc[rt][1]);
                acc[rt][1] = mfma16(al[rt], bh1, acc[rt][1]);
            }
        }
        __syncthreads();   // prior phase-2 readers of Wx are done
        // ---- unscale (W was *16), add bias, split -> LDS ----
        #pragma unroll
        for (int rt = 0; rt < 3; ++rt) {
            #pragma unroll
            for (int j2 = 0; j2 < 2; ++j2) {
                const float wb = wbv[h][j2];
                const int cl = (j2 ? (wave + 4) : wave) * 16 + l15;
                #pragma unroll
                for (int r = 0; r < 4; ++r) {
                    const int row = rt * 16 + quad * 4 + r;
                    float v = acc[rt][j2][r] * 0.0625f + wb;
                    f16 hh = (f16)v;
                    Wxh[row * WXSTR + cl] = hh;
                    Wxl[row * WXSTR + cl] = (f16)(v - (float)hh);
                }
            }
        }
        __syncthreads();
        // ===== phase 2: S += Wx[:, half] * X[:, half]^T (9 tiles over 4 waves, static acc idx) =====
        #pragma unroll
        for (int it = 0; it < 3; ++it) {
            const int p = wave + it * 4;
            if (p < 9) {
                const int nt = p / 3, mt = p % 3;
                const f16* wxh_p = Wxh + (nt * 16 + l15) * WXSTR + quad * 8;
                const f16* wxl_p = Wxl + (nt * 16 + l15) * WXSTR + quad * 8;
                #pragma unroll
                for (int kc2 = 0; kc2 < 4; ++kc2) {
                    f16x8 pah = *(const f16x8*)(wxh_p + kc2 * 32);
                    f16x8 pal = *(const f16x8*)(wxl_p + kc2 * 32);
                    f16x8 pbh = Xh[(mt * 8 + h * 4 + kc2) * 64 + lane];
                    f16x8 pbl = Xl[(mt * 8 + h * 4 + kc2) * 64 + lane];
                    sacc[it] = mfma16(pah, pbh, sacc[it]);
                    sacc[it] = mfma16(pah, pbl, sacc[it]);
                    sacc[it] = mfma16(pal, pbh, sacc[it]);
                }
            }
        }
    }

    // ===== epilogue: T = tanh(S + v1 + v2) -> Ts (overlays Wxh), then U-dot =====
    __syncthreads();
    float* Ts = (float*)Wxh;   // 1296 f32 = 5184 B
    #pragma unroll
    for (int it = 0; it < 3; ++it) {
        const int p = wave + it * 4;
        if (p < 9) {
            const int nt = p / 3, mt = p % 3;
            const int m = mt * 16 + l15;
            if (m < NF) {
                #pragma unroll
                for (int r = 0; r < 4; ++r) {
                    const int n = nt * 16 + quad * 4 + r;
                    if (n < NF) {
                        float sv = sacc[it][r] + v1s[n] + v2s[m];
                        float e = __expf(2.f * sv);
                        Ts[n * NF + m] = 1.f - 2.f / (e + 1.f);
                    }
                }
            }
        }
    }
    __syncthreads();
    if (t < QPK) {
        const float* tp = Ts + t * 8;
        float lg = Uws[8];
        #pragma unroll
        for (int j = 0; j < 8; ++j) lg += Uws[j] * tp[j];
        logits[(size_t)b * NN2 + k * QPK + t] = lg;
    }
}

// ---- in-place row softmax: 4 rows per 256-thread block (one per wave) ----
__global__ __launch_bounds__(256) void softmax_rows(float* __restrict__ out) {
    int row = blockIdx.x * 4 + (threadIdx.x >> 6);
    int t = threadIdx.x & 63;
    float* p = out + (size_t)row * NF;
    float v = (t < NF) ? p[t] : -INFINITY;
    float mx = v;
    #pragma unroll
    for (int off = 32; off > 0; off >>= 1) mx = fmaxf(mx, __shfl_xor(mx, off));
    float e = (t < NF) ? __expf(v - mx) : 0.f;
    float sm = e;
    #pragma unroll
    for (int off = 32; off > 0; off >>= 1) sm += __shfl_xor(sm, off);
    if (t < NF) p[t] = e / sm;
}

extern "C" void kernel_launch(void* const* d_in, const int* in_sizes, int n_in,
                              void* d_out, int out_size, void* d_ws, size_t ws_size,
                              hipStream_t stream) {
    const float* texts = (const float*)d_in[0];
    const float* W     = (const float*)d_in[1];
    const float* Wb    = (const float*)d_in[2];
    const float* V1w   = (const float*)d_in[3];
    const float* V1b   = (const float*)d_in[4];
    const float* V2w   = (const float*)d_in[5];
    const float* V2b   = (const float*)d_in[6];
    const float* Uw    = (const float*)d_in[7];
    const float* Ub    = (const float*)d_in[8];

    char* ws = (char*)d_ws;
    f16x8* WfH = (f16x8*)ws;                                   //  1 MiB
    f16x8* WfL = (f16x8*)(ws + (1 << 20));                     //  1 MiB
    f16x8* XfH = (f16x8*)(ws + (2 << 20));                     // 24 MiB
    f16x8* XfL = (f16x8*)(ws + (2 << 20) + (size_t)NB * NFRAG * 16);       // 24 MiB
    float* v12 = (float*)(ws + (2 << 20) + (size_t)2 * NB * NFRAG * 16);   // 2.25 MiB
    float* logits = (float*)d_out;

    hipFuncSetAttribute((const void*)ntn_main,
                        hipFuncAttributeMaxDynamicSharedMemorySize, SMEM_BYTES);

    prep_w<<<256, 256, 0, stream>>>(W, WfH, WfL);
    prep_x<<<NB, 256, 0, stream>>>(texts, XfH, XfL, V1w, V1b, V2w, V2b, v12);
    ntn_main<<<NB * NK, 256, SMEM_BYTES, stream>>>(XfH, XfL, WfH, WfL, Wb, v12, Uw, Ub, logits);
    softmax_rows<<<NB * NF / 4, 256, 0, stream>>>(logits);
}

// Round 5
// 309.103 us; speedup vs baseline: 2.1979x; 1.0516x over previous
//
#include <hip/hip_runtime.h>
#include <math.h>

#define NB 1024
#define NF 36
#define ED 256
#define NK 8
#define NN2 1296   // 36*36
#define QPK 162    // 1296/8

typedef _Float16 f16;
typedef f16 f16x8 __attribute__((ext_vector_type(8)));
typedef float f32x4 __attribute__((ext_vector_type(4)));

#define WXSTR 136     // f16 per Wx half-row (128 + 8 pad); 272B = 17*16 (b128-aligned)
#define NFRAG 1536    // 3 row-tiles * 8 kc * 64 lanes, f16x8 each, per hi/lo component

// ---- ntn_main LDS layout (dynamic) ----
#define XH_OFF  0
#define XL_OFF  24576
#define WXH_OFF 49152
#define WXL_OFF 62208
#define V_OFF   75264
#define SMEM_MAIN (V_OFF + (NF + NF + 9) * 4)   // 75588 -> 2 blocks/CU

// ---- prep_all LDS layout (dynamic, 64 KiB) ----
#define PXH_OFF 0
#define PXL_OFF 24576
#define PVH_OFF 49152
#define PVL_OFF 57344
#define SMEM_PREP 65536

__device__ __forceinline__ f32x4 mfma16(f16x8 a, f16x8 b, f32x4 c) {
    return __builtin_amdgcn_mfma_f32_16x16x32_f16(a, b, c, 0, 0, 0);
}

// Merged prep: blocks [0,256) pack W -> B-frag order (scaled by 16 to keep lo
// fp16-normal); blocks [256,1280) split X into fragment-order hi/lo (LDS +
// global) and compute v12 = [V1;V2].X^T via split MFMA.
__global__ __launch_bounds__(256) void prep_all(
    const float* __restrict__ W, f16x8* __restrict__ WfH, f16x8* __restrict__ WfL,
    const float* __restrict__ texts, f16x8* __restrict__ XfH, f16x8* __restrict__ XfL,
    const float* __restrict__ V1w, const float* __restrict__ V1b,
    const float* __restrict__ V2w, const float* __restrict__ V2b,
    float* __restrict__ v12)
{
    extern __shared__ char psmem[];
    const int blk = blockIdx.x;
    const int t = threadIdx.x;

    if (blk < 256) {   // ---- W fragment pack ----
        int idx = blk * 256 + t;       // 65536 total
        int dox = idx & 31;
        int c   = (idx >> 5) & 255;
        int k   = idx >> 13;
        const float* src = W + ((size_t)(k * 256 + c)) * 256 + dox * 8;
        float4 a = *(const float4*)src;
        float4 b = *(const float4*)(src + 4);
        float v[8] = {a.x, a.y, a.z, a.w, b.x, b.y, b.z, b.w};
        f16x8 hi, lo;
        #pragma unroll
        for (int j = 0; j < 8; ++j) {
            float sv = v[j] * 16.0f;
            f16 h = (f16)sv;
            hi[j] = h;
            lo[j] = (f16)(sv - (float)h);
        }
        int kc = dox >> 2, qd = dox & 3, ct = c >> 4;
        int fr = ((k * 16 + ct) * 8 + kc) * 64 + qd * 16 + (c & 15);
        WfH[fr] = hi;
        WfL[fr] = lo;
        return;
    }

    // ---- X fragment pack + v12 via MFMA ----
    f16x8* XsH = (f16x8*)(psmem + PXH_OFF);
    f16x8* XsL = (f16x8*)(psmem + PXL_OFF);
    f16x8* VfH = (f16x8*)(psmem + PVH_OFF);
    f16x8* VfL = (f16x8*)(psmem + PVL_OFF);

    const int b = blk - 256;
    const float* xb = texts + (size_t)b * NF * ED;

    // V fragments: col = which*8 + k at lane&15; scaled by 16
    #pragma unroll
    for (int i0 = 0; i0 < 2; ++i0) {
        int i = t + i0 * 256;          // [0,512)
        int kc = (i >> 6) & 7, lane = i & 63;
        int q = lane >> 4, col = lane & 15;
        int which = col >> 3, kk = col & 7;
        const float* src = (which ? V2w : V1w) + kk * 256 + kc * 32 + q * 8;
        f16x8 hi, lo;
        #pragma unroll
        for (int j = 0; j < 8; ++j) {
            float sv = src[j] * 16.0f;
            f16 h = (f16)sv;
            hi[j] = h;
            lo[j] = (f16)(sv - (float)h);
        }
        VfH[i] = hi;
        VfL[i] = lo;
    }

    // X fragments: XsH[(rt*8+kc)*64 + q*16+l15] = X[rt*16+l15][kc*32+q*8..+7]
    #pragma unroll
    for (int i0 = 0; i0 < 6; ++i0) {
        int i = t + i0 * 256;          // [0,1536)
        int rt = i >> 9, kc = (i >> 6) & 7, lane = i & 63;
        int q = lane >> 4, l15 = lane & 15;
        int row = rt * 16 + l15;
        f16x8 hi, lo;
        if (row < NF) {
            const float* s = xb + row * ED + kc * 32 + q * 8;
            float4 a = *(const float4*)s;
            float4 c = *(const float4*)(s + 4);
            float v[8] = {a.x, a.y, a.z, a.w, c.x, c.y, c.z, c.w};
            #pragma unroll
            for (int j = 0; j < 8; ++j) {
                f16 h = (f16)v[j];
                hi[j] = h;
                lo[j] = (f16)(v[j] - (float)h);
            }
        } else {
            #pragma unroll
            for (int j = 0; j < 8; ++j) { hi[j] = (f16)0.f; lo[j] = (f16)0.f; }
        }
        XsH[i] = hi;
        XsL[i] = lo;
        XfH[(size_t)b * NFRAG + i] = hi;
        XfL[(size_t)b * NFRAG + i] = lo;
    }
    __syncthreads();

    // v12 MFMA: wave w (<3) handles row-tile rt=w
    const int wave = t >> 6, lane = t & 63;
    const int q = lane >> 4, l15 = lane & 15;
    if (wave < 3) {
        f32x4 acc = (f32x4){0.f, 0.f, 0.f, 0.f};
        #pragma unroll
        for (int kc = 0; kc < 8; ++kc) {
            f16x8 ah = XsH[(wave * 8 + kc) * 64 + lane];
            f16x8 al = XsL[(wave * 8 + kc) * 64 + lane];
            f16x8 bh = VfH[kc * 64 + lane];
            f16x8 bl = VfL[kc * 64 + lane];
            acc = mfma16(ah, bh, acc);
            acc = mfma16(ah, bl, acc);
            acc = mfma16(al, bh, acc);
        }
        const int which = l15 >> 3, kk = l15 & 7;
        const float bias = which ? V2b[kk] : V1b[kk];
        #pragma unroll
        for (int r = 0; r < 4; ++r) {
            const int n = wave * 16 + q * 4 + r;
            if (n < NF)
                v12[((size_t)b * 16 + l15) * NF + n] = acc[r] * 0.0625f + bias;
        }
    }
}

__global__ __launch_bounds__(256, 2) void ntn_main(
    const f16x8* __restrict__ XfHG, const f16x8* __restrict__ XfLG,
    const f16x8* __restrict__ WfH, const f16x8* __restrict__ WfL,
    const float* __restrict__ Wb, const float* __restrict__ v12,
    const float* __restrict__ Uw, const float* __restrict__ Ubp,
    float* __restrict__ logits)
{
    extern __shared__ char smem[];
    f16x8* Xh  = (f16x8*)(smem + XH_OFF);
    f16x8* Xl  = (f16x8*)(smem + XL_OFF);
    f16*   Wxh = (f16*)(smem + WXH_OFF);
    f16*   Wxl = (f16*)(smem + WXL_OFF);
    float* v1s = (float*)(smem + V_OFF);
    float* v2s = v1s + NF;
    float* Uws = v2s + NF;

    // XCD swizzle: all 8 k's of a b share id%8 (same XCD -> X L2-resident)
    const int id  = blockIdx.x;
    const int rem = id >> 3;
    const int k   = rem & 7;
    const int b   = ((rem >> 3) << 3) | (id & 7);

    const int t    = threadIdx.x;
    const int wave = t >> 6;
    const int lane = t & 63;
    const int quad = lane >> 4;
    const int l15  = lane & 15;

    // ---- stage X fragments into LDS (coalesced dwordx4) ----
    {
        const f16x8* gh = XfHG + (size_t)b * NFRAG;
        const f16x8* gl = XfLG + (size_t)b * NFRAG;
        #pragma unroll
        for (int i = 0; i < 6; ++i) Xh[t + i * 256] = gh[t + i * 256];
        #pragma unroll
        for (int i = 0; i < 6; ++i) Xl[t + i * 256] = gl[t + i * 256];
    }
    if (t < 72) {
        const int which = (t >= NF);
        const int n = t - which * NF;
        float v = v12[((size_t)b * 16 + which * 8 + k) * NF + n];
        if (which) v2s[n] = v; else v1s[n] = v;
    }
    if (t < 8) Uws[t] = Uw[t];
    if (t == 8) Uws[8] = Ubp[0];

    float wbv[2][2];
    #pragma unroll
    for (int h = 0; h < 2; ++h) {
        wbv[h][0] = Wb[k * ED + (h * 8 + wave) * 16 + l15];
        wbv[h][1] = Wb[k * ED + (h * 8 + wave + 4) * 16 + l15];
    }
    __syncthreads();

    const f16x8* WfHk = WfH + (size_t)k * 16 * 8 * 64;
    const f16x8* WfLk = WfL + (size_t)k * 16 * 8 * 64;

    f32x4 sacc[3];
    #pragma unroll
    for (int i = 0; i < 3; ++i) sacc[i] = (f32x4){0.f, 0.f, 0.f, 0.f};

    for (int h = 0; h < 2; ++h) {
        // ===== phase 1: Wx[:, half h] = X * W[k]^T (AhBh + AhBl + AlBh) =====
        f32x4 acc[3][2];
        #pragma unroll
        for (int i = 0; i < 3; ++i) { acc[i][0] = (f32x4){0,0,0,0}; acc[i][1] = (f32x4){0,0,0,0}; }
        const int ct0 = h * 8 + wave;
        const int ct1 = ct0 + 4;
        #pragma unroll   // full unroll: all 32 W-frag L2 loads issue up front
        for (int kc = 0; kc < 8; ++kc) {
            f16x8 ah[3], al[3];
            #pragma unroll
            for (int rt = 0; rt < 3; ++rt) {
                ah[rt] = Xh[(rt * 8 + kc) * 64 + lane];   // ds_read_b128
                al[rt] = Xl[(rt * 8 + kc) * 64 + lane];
            }
            f16x8 bh0 = WfHk[(ct0 * 8 + kc) * 64 + lane];
            f16x8 bl0 = WfLk[(ct0 * 8 + kc) * 64 + lane];
            f16x8 bh1 = WfHk[(ct1 * 8 + kc) * 64 + lane];
            f16x8 bl1 = WfLk[(ct1 * 8 + kc) * 64 + lane];
            #pragma unroll
            for (int rt = 0; rt < 3; ++rt) {
                acc[rt][0] = mfma16(ah[rt], bh0, acc[rt][0]);
                acc[rt][0] = mfma16(ah[rt], bl0, acc[rt][0]);
                acc[rt][0] = mfma16(al[rt], bh0, acc[rt][0]);
                acc[rt][1] = mfma16(ah[rt], bh1, acc[rt][1]);
                acc[rt][1] = mfma16(ah[rt], bl1, acc[rt][1]);
                acc[rt][1] = mfma16(al[rt], bh1, acc[rt][1]);
            }
        }
        __syncthreads();   // prior phase-2 readers of Wx are done
        // ---- unscale (W was *16), add bias, split -> LDS ----
        #pragma unroll
        for (int rt = 0; rt < 3; ++rt) {
            #pragma unroll
            for (int j2 = 0; j2 < 2; ++j2) {
                const float wb = wbv[h][j2];
                const int cl = (j2 ? (wave + 4) : wave) * 16 + l15;
                #pragma unroll
                for (int r = 0; r < 4; ++r) {
                    const int row = rt * 16 + quad * 4 + r;
                    float v = acc[rt][j2][r] * 0.0625f + wb;
                    f16 hh = (f16)v;
                    Wxh[row * WXSTR + cl] = hh;
                    Wxl[row * WXSTR + cl] = (f16)(v - (float)hh);
                }
            }
        }
        __syncthreads();
        // ===== phase 2: S += Wx[:, half] * X[:, half]^T (static acc idx) =====
        #pragma unroll
        for (int it = 0; it < 3; ++it) {
            const int p = wave + it * 4;
            if (p < 9) {
                const int nt = p / 3, mt = p % 3;
                const f16* wxh_p = Wxh + (nt * 16 + l15) * WXSTR + quad * 8;
                const f16* wxl_p = Wxl + (nt * 16 + l15) * WXSTR + quad * 8;
                #pragma unroll
                for (int kc2 = 0; kc2 < 4; ++kc2) {
                    f16x8 pah = *(const f16x8*)(wxh_p + kc2 * 32);
                    f16x8 pal = *(const f16x8*)(wxl_p + kc2 * 32);
                    f16x8 pbh = Xh[(mt * 8 + h * 4 + kc2) * 64 + lane];
                    f16x8 pbl = Xl[(mt * 8 + h * 4 + kc2) * 64 + lane];
                    sacc[it] = mfma16(pah, pbh, sacc[it]);
                    sacc[it] = mfma16(pah, pbl, sacc[it]);
                    sacc[it] = mfma16(pal, pbh, sacc[it]);
                }
            }
        }
    }

    // ===== epilogue: T = tanh(S + v1 + v2) -> Ts (overlays Wxh), U-dot =====
    __syncthreads();
    float* Ts = (float*)Wxh;   // 1296 f32 = 5184 B
    #pragma unroll
    for (int it = 0; it < 3; ++it) {
        const int p = wave + it * 4;
        if (p < 9) {
            const int nt = p / 3, mt = p % 3;
            const int m = mt * 16 + l15;
            if (m < NF) {
                #pragma unroll
                for (int r = 0; r < 4; ++r) {
                    const int n = nt * 16 + quad * 4 + r;
                    if (n < NF) {
                        float sv = sacc[it][r] + v1s[n] + v2s[m];
                        float e = __expf(2.f * sv);
                        Ts[n * NF + m] = 1.f - 2.f / (e + 1.f);
                    }
                }
            }
        }
    }
    __syncthreads();
    if (t < QPK) {
        const float* tp = Ts + t * 8;
        float lg = Uws[8];
        #pragma unroll
        for (int j = 0; j < 8; ++j) lg += Uws[j] * tp[j];
        logits[(size_t)b * NN2 + k * QPK + t] = lg;
    }
}

// ---- in-place row softmax: 4 rows per 256-thread block (one per wave) ----
__global__ __launch_bounds__(256) void softmax_rows(float* __restrict__ out) {
    int row = blockIdx.x * 4 + (threadIdx.x >> 6);
    int t = threadIdx.x & 63;
    float* p = out + (size_t)row * NF;
    float v = (t < NF) ? p[t] : -INFINITY;
    float mx = v;
    #pragma unroll
    for (int off = 32; off > 0; off >>= 1) mx = fmaxf(mx, __shfl_xor(mx, off));
    float e = (t < NF) ? __expf(v - mx) : 0.f;
    float sm = e;
    #pragma unroll
    for (int off = 32; off > 0; off >>= 1) sm += __shfl_xor(sm, off);
    if (t < NF) p[t] = e / sm;
}

extern "C" void kernel_launch(void* const* d_in, const int* in_sizes, int n_in,
                              void* d_out, int out_size, void* d_ws, size_t ws_size,
                              hipStream_t stream) {
    const float* texts = (const float*)d_in[0];
    const float* W     = (const float*)d_in[1];
    const float* Wb    = (const float*)d_in[2];
    const float* V1w   = (const float*)d_in[3];
    const float* V1b   = (const float*)d_in[4];
    const float* V2w   = (const float*)d_in[5];
    const float* V2b   = (const float*)d_in[6];
    const float* Uw    = (const float*)d_in[7];
    const float* Ub    = (const float*)d_in[8];

    char* ws = (char*)d_ws;
    f16x8* WfH = (f16x8*)ws;                                   //  1 MiB
    f16x8* WfL = (f16x8*)(ws + (1 << 20));                     //  1 MiB
    f16x8* XfH = (f16x8*)(ws + (2 << 20));                     // 24 MiB
    f16x8* XfL = (f16x8*)(ws + (2 << 20) + (size_t)NB * NFRAG * 16);       // 24 MiB
    float* v12 = (float*)(ws + (2 << 20) + (size_t)2 * NB * NFRAG * 16);   // 2.25 MiB
    float* logits = (float*)d_out;

    hipFuncSetAttribute((const void*)prep_all,
                        hipFuncAttributeMaxDynamicSharedMemorySize, SMEM_PREP);
    hipFuncSetAttribute((const void*)ntn_main,
                        hipFuncAttributeMaxDynamicSharedMemorySize, SMEM_MAIN);

    prep_all<<<256 + NB, 256, SMEM_PREP, stream>>>(W, WfH, WfL, texts, XfH, XfL,
                                                   V1w, V1b, V2w, V2b, v12);
    ntn_main<<<NB * NK, 256, SMEM_MAIN, stream>>>(XfH, XfL, WfH, WfL, Wb, v12, Uw, Ub, logits);
    softmax_rows<<<NB * NF / 4, 256, 0, stream>>>(logits);
}

// Round 6
// 303.219 us; speedup vs baseline: 2.2405x; 1.0194x over previous
//
#include <hip/hip_runtime.h>
#include <math.h>

#define NB 1024
#define NF 36
#define ED 256
#define NK 8
#define NN2 1296   // 36*36
#define QPK 162    // 1296/8

typedef _Float16 f16;
typedef f16 f16x8 __attribute__((ext_vector_type(8)));
typedef float f32x4 __attribute__((ext_vector_type(4)));

#define WXSTR 136     // f16 per Wx half-row (128 + 8 pad); 272B = 17*16 (b128-aligned)
#define NFRAG 1536    // 3 row-tiles * 8 kc * 64 lanes, f16x8 each, per hi/lo component

// ---- ntn_main LDS layout (dynamic): Xh | Wxh | Wxl | v  == 51 KB -> 3 blocks/CU ----
#define XH_OFF  0
#define WXH_OFF 24576
#define WXL_OFF 37632
#define V_OFF   50688
#define SMEM_MAIN (V_OFF + (NF + NF + 9) * 4)   // 51012

// ---- prep_all LDS layout (dynamic, 64 KiB) ----
#define PXH_OFF 0
#define PXL_OFF 24576
#define PVH_OFF 49152
#define PVL_OFF 57344
#define SMEM_PREP 65536

__device__ __forceinline__ f32x4 mfma16(f16x8 a, f16x8 b, f32x4 c) {
    return __builtin_amdgcn_mfma_f32_16x16x32_f16(a, b, c, 0, 0, 0);
}

// Merged prep: blocks [0,256) pack W -> B-frag order (scaled by 16 to keep lo
// fp16-normal); blocks [256,1280) split X into fragment-order hi/lo and
// compute v12 = [V1;V2].X^T via split MFMA.
__global__ __launch_bounds__(256) void prep_all(
    const float* __restrict__ W, f16x8* __restrict__ WfH, f16x8* __restrict__ WfL,
    const float* __restrict__ texts, f16x8* __restrict__ XfH, f16x8* __restrict__ XfL,
    const float* __restrict__ V1w, const float* __restrict__ V1b,
    const float* __restrict__ V2w, const float* __restrict__ V2b,
    float* __restrict__ v12)
{
    extern __shared__ char psmem[];
    const int blk = blockIdx.x;
    const int t = threadIdx.x;

    if (blk < 256) {   // ---- W fragment pack ----
        int idx = blk * 256 + t;       // 65536 total
        int dox = idx & 31;
        int c   = (idx >> 5) & 255;
        int k   = idx >> 13;
        const float* src = W + ((size_t)(k * 256 + c)) * 256 + dox * 8;
        float4 a = *(const float4*)src;
        float4 b = *(const float4*)(src + 4);
        float v[8] = {a.x, a.y, a.z, a.w, b.x, b.y, b.z, b.w};
        f16x8 hi, lo;
        #pragma unroll
        for (int j = 0; j < 8; ++j) {
            float sv = v[j] * 16.0f;
            f16 h = (f16)sv;
            hi[j] = h;
            lo[j] = (f16)(sv - (float)h);
        }
        int kc = dox >> 2, qd = dox & 3, ct = c >> 4;
        int fr = ((k * 16 + ct) * 8 + kc) * 64 + qd * 16 + (c & 15);
        WfH[fr] = hi;
        WfL[fr] = lo;
        return;
    }

    // ---- X fragment pack + v12 via MFMA ----
    f16x8* XsH = (f16x8*)(psmem + PXH_OFF);
    f16x8* XsL = (f16x8*)(psmem + PXL_OFF);
    f16x8* VfH = (f16x8*)(psmem + PVH_OFF);
    f16x8* VfL = (f16x8*)(psmem + PVL_OFF);

    const int b = blk - 256;
    const float* xb = texts + (size_t)b * NF * ED;

    // V fragments: col = which*8 + k at lane&15; scaled by 16
    #pragma unroll
    for (int i0 = 0; i0 < 2; ++i0) {
        int i = t + i0 * 256;          // [0,512)
        int kc = (i >> 6) & 7, lane = i & 63;
        int q = lane >> 4, col = lane & 15;
        int which = col >> 3, kk = col & 7;
        const float* src = (which ? V2w : V1w) + kk * 256 + kc * 32 + q * 8;
        f16x8 hi, lo;
        #pragma unroll
        for (int j = 0; j < 8; ++j) {
            float sv = src[j] * 16.0f;
            f16 h = (f16)sv;
            hi[j] = h;
            lo[j] = (f16)(sv - (float)h);
        }
        VfH[i] = hi;
        VfL[i] = lo;
    }

    // X fragments: XsH[(rt*8+kc)*64 + q*16+l15] = X[rt*16+l15][kc*32+q*8..+7]
    #pragma unroll
    for (int i0 = 0; i0 < 6; ++i0) {
        int i = t + i0 * 256;          // [0,1536)
        int rt = i >> 9, kc = (i >> 6) & 7, lane = i & 63;
        int q = lane >> 4, l15 = lane & 15;
        int row = rt * 16 + l15;
        f16x8 hi, lo;
        if (row < NF) {
            const float* s = xb + row * ED + kc * 32 + q * 8;
            float4 a = *(const float4*)s;
            float4 c = *(const float4*)(s + 4);
            float v[8] = {a.x, a.y, a.z, a.w, c.x, c.y, c.z, c.w};
            #pragma unroll
            for (int j = 0; j < 8; ++j) {
                f16 h = (f16)v[j];
                hi[j] = h;
                lo[j] = (f16)(v[j] - (float)h);
            }
        } else {
            #pragma unroll
            for (int j = 0; j < 8; ++j) { hi[j] = (f16)0.f; lo[j] = (f16)0.f; }
        }
        XsH[i] = hi;
        XsL[i] = lo;
        XfH[(size_t)b * NFRAG + i] = hi;
        XfL[(size_t)b * NFRAG + i] = lo;
    }
    __syncthreads();

    // v12 MFMA: wave w (<3) handles row-tile rt=w
    const int wave = t >> 6, lane = t & 63;
    const int q = lane >> 4, l15 = lane & 15;
    if (wave < 3) {
        f32x4 acc = (f32x4){0.f, 0.f, 0.f, 0.f};
        #pragma unroll
        for (int kc = 0; kc < 8; ++kc) {
            f16x8 ah = XsH[(wave * 8 + kc) * 64 + lane];
            f16x8 al = XsL[(wave * 8 + kc) * 64 + lane];
            f16x8 bh = VfH[kc * 64 + lane];
            f16x8 bl = VfL[kc * 64 + lane];
            acc = mfma16(ah, bh, acc);
            acc = mfma16(ah, bl, acc);
            acc = mfma16(al, bh, acc);
        }
        const int which = l15 >> 3, kk = l15 & 7;
        const float bias = which ? V2b[kk] : V1b[kk];
        #pragma unroll
        for (int r = 0; r < 4; ++r) {
            const int n = wave * 16 + q * 4 + r;
            if (n < NF)
                v12[((size_t)b * 16 + l15) * NF + n] = acc[r] * 0.0625f + bias;
        }
    }
}

__global__ __launch_bounds__(256, 3) void ntn_main(
    const f16x8* __restrict__ XfHG, const f16x8* __restrict__ XfLG,
    const f16x8* __restrict__ WfH, const f16x8* __restrict__ WfL,
    const float* __restrict__ Wb, const float* __restrict__ v12,
    const float* __restrict__ Uw, const float* __restrict__ Ubp,
    float* __restrict__ logits)
{
    extern __shared__ char smem[];
    f16x8* Xh  = (f16x8*)(smem + XH_OFF);
    f16*   Wxh = (f16*)(smem + WXH_OFF);
    f16*   Wxl = (f16*)(smem + WXL_OFF);
    float* v1s = (float*)(smem + V_OFF);
    float* v2s = v1s + NF;
    float* Uws = v2s + NF;

    // XCD swizzle: all 8 k's of a b share id%8 (same XCD -> X/W L2-resident)
    const int id  = blockIdx.x;
    const int rem = id >> 3;
    const int k   = rem & 7;
    const int b   = ((rem >> 3) << 3) | (id & 7);

    const int t    = threadIdx.x;
    const int wave = t >> 6;
    const int lane = t & 63;
    const int quad = lane >> 4;
    const int l15  = lane & 15;

    const f16x8* Xlg = XfLG + (size_t)b * NFRAG;   // X-lo frags: global/L2 (L1-broadcast across waves)

    // ---- stage X-hi fragments into LDS (coalesced dwordx4) ----
    {
        const f16x8* gh = XfHG + (size_t)b * NFRAG;
        #pragma unroll
        for (int i = 0; i < 6; ++i) Xh[t + i * 256] = gh[t + i * 256];
    }
    if (t < 72) {
        const int which = (t >= NF);
        const int n = t - which * NF;
        float v = v12[((size_t)b * 16 + which * 8 + k) * NF + n];
        if (which) v2s[n] = v; else v1s[n] = v;
    }
    if (t < 8) Uws[t] = Uw[t];
    if (t == 8) Uws[8] = Ubp[0];

    float wbv[2][2];
    #pragma unroll
    for (int h = 0; h < 2; ++h) {
        wbv[h][0] = Wb[k * ED + (h * 8 + wave) * 16 + l15];
        wbv[h][1] = Wb[k * ED + (h * 8 + wave + 4) * 16 + l15];
    }
    __syncthreads();

    const f16x8* WfHk = WfH + (size_t)k * 16 * 8 * 64;
    const f16x8* WfLk = WfL + (size_t)k * 16 * 8 * 64;

    f32x4 sacc[3];
    #pragma unroll
    for (int i = 0; i < 3; ++i) sacc[i] = (f32x4){0.f, 0.f, 0.f, 0.f};

    for (int h = 0; h < 2; ++h) {
        // ===== phase 1: Wx[:, half h] = X * W[k]^T (AhBh + AhBl + AlBh) =====
        f32x4 acc[3][2];
        #pragma unroll
        for (int i = 0; i < 3; ++i) { acc[i][0] = (f32x4){0,0,0,0}; acc[i][1] = (f32x4){0,0,0,0}; }
        const int ct0 = h * 8 + wave;
        const int ct1 = ct0 + 4;
        #pragma unroll 2
        for (int kc = 0; kc < 8; ++kc) {
            f16x8 ah[3], al[3];
            #pragma unroll
            for (int rt = 0; rt < 3; ++rt) {
                ah[rt] = Xh[(rt * 8 + kc) * 64 + lane];    // LDS ds_read_b128
                al[rt] = Xlg[(rt * 8 + kc) * 64 + lane];   // global (L2/L1)
            }
            f16x8 bh0 = WfHk[(ct0 * 8 + kc) * 64 + lane];
            f16x8 bl0 = WfLk[(ct0 * 8 + kc) * 64 + lane];
            f16x8 bh1 = WfHk[(ct1 * 8 + kc) * 64 + lane];
            f16x8 bl1 = WfLk[(ct1 * 8 + kc) * 64 + lane];
            #pragma unroll
            for (int rt = 0; rt < 3; ++rt) {
                acc[rt][0] = mfma16(ah[rt], bh0, acc[rt][0]);
                acc[rt][0] = mfma16(ah[rt], bl0, acc[rt][0]);
                acc[rt][0] = mfma16(al[rt], bh0, acc[rt][0]);
                acc[rt][1] = mfma16(ah[rt], bh1, acc[rt][1]);
                acc[rt][1] = mfma16(ah[rt], bl1, acc[rt][1]);
                acc[rt][1] = mfma16(al[rt], bh1, acc[rt][1]);
            }
        }
        __syncthreads();   // prior phase-2 readers of Wx are done
        // ---- unscale (W was *16), add bias, split -> LDS ----
        #pragma unroll
        for (int rt = 0; rt < 3; ++rt) {
            #pragma unroll
            for (int j2 = 0; j2 < 2; ++j2) {
                const float wb = wbv[h][j2];
                const int cl = (j2 ? (wave + 4) : wave) * 16 + l15;
                #pragma unroll
                for (int r = 0; r < 4; ++r) {
                    const int row = rt * 16 + quad * 4 + r;
                    float v = acc[rt][j2][r] * 0.0625f + wb;
                    f16 hh = (f16)v;
                    Wxh[row * WXSTR + cl] = hh;
                    Wxl[row * WXSTR + cl] = (f16)(v - (float)hh);
                }
            }
        }
        __syncthreads();
        // ===== phase 2: S += Wx[:, half] * X[:, half]^T (static acc idx) =====
        #pragma unroll
        for (int it = 0; it < 3; ++it) {
            const int p = wave + it * 4;
            if (p < 9) {
                const int nt = p / 3, mt = p % 3;
                const f16* wxh_p = Wxh + (nt * 16 + l15) * WXSTR + quad * 8;
                const f16* wxl_p = Wxl + (nt * 16 + l15) * WXSTR + quad * 8;
                #pragma unroll
                for (int kc2 = 0; kc2 < 4; ++kc2) {
                    f16x8 pah = *(const f16x8*)(wxh_p + kc2 * 32);
                    f16x8 pal = *(const f16x8*)(wxl_p + kc2 * 32);
                    f16x8 pbh = Xh[(mt * 8 + h * 4 + kc2) * 64 + lane];
                    f16x8 pbl = Xlg[(mt * 8 + h * 4 + kc2) * 64 + lane];
                    sacc[it] = mfma16(pah, pbh, sacc[it]);
                    sacc[it] = mfma16(pah, pbl, sacc[it]);
                    sacc[it] = mfma16(pal, pbh, sacc[it]);
                }
            }
        }
    }

    // ===== epilogue: T = tanh(S + v1 + v2) -> Ts (overlays Wxh), U-dot =====
    __syncthreads();
    float* Ts = (float*)Wxh;   // 1296 f32 = 5184 B
    #pragma unroll
    for (int it = 0; it < 3; ++it) {
        const int p = wave + it * 4;
        if (p < 9) {
            const int nt = p / 3, mt = p % 3;
            const int m = mt * 16 + l15;
            if (m < NF) {
                #pragma unroll
                for (int r = 0; r < 4; ++r) {
                    const int n = nt * 16 + quad * 4 + r;
                    if (n < NF) {
                        float sv = sacc[it][r] + v1s[n] + v2s[m];
                        float e = __expf(2.f * sv);
                        Ts[n * NF + m] = 1.f - 2.f / (e + 1.f);
                    }
                }
            }
        }
    }
    __syncthreads();
    if (t < QPK) {
        const float* tp = Ts + t * 8;
        float lg = Uws[8];
        #pragma unroll
        for (int j = 0; j < 8; ++j) lg += Uws[j] * tp[j];
        logits[(size_t)b * NN2 + k * QPK + t] = lg;
    }
}

// ---- in-place row softmax: 4 rows per 256-thread block (one per wave) ----
__global__ __launch_bounds__(256) void softmax_rows(float* __restrict__ out) {
    int row = blockIdx.x * 4 + (threadIdx.x >> 6);
    int t = threadIdx.x & 63;
    float* p = out + (size_t)row * NF;
    float v = (t < NF) ? p[t] : -INFINITY;
    float mx = v;
    #pragma unroll
    for (int off = 32; off > 0; off >>= 1) mx = fmaxf(mx, __shfl_xor(mx, off));
    float e = (t < NF) ? __expf(v - mx) : 0.f;
    float sm = e;
    #pragma unroll
    for (int off = 32; off > 0; off >>= 1) sm += __shfl_xor(sm, off);
    if (t < NF) p[t] = e / sm;
}

extern "C" void kernel_launch(void* const* d_in, const int* in_sizes, int n_in,
                              void* d_out, int out_size, void* d_ws, size_t ws_size,
                              hipStream_t stream) {
    const float* texts = (const float*)d_in[0];
    const float* W     = (const float*)d_in[1];
    const float* Wb    = (const float*)d_in[2];
    const float* V1w   = (const float*)d_in[3];
    const float* V1b   = (const float*)d_in[4];
    const float* V2w   = (const float*)d_in[5];
    const float* V2b   = (const float*)d_in[6];
    const float* Uw    = (const float*)d_in[7];
    const float* Ub    = (const float*)d_in[8];

    char* ws = (char*)d_ws;
    f16x8* WfH = (f16x8*)ws;                                   //  1 MiB
    f16x8* WfL = (f16x8*)(ws + (1 << 20));                     //  1 MiB
    f16x8* XfH = (f16x8*)(ws + (2 << 20));                     // 24 MiB
    f16x8* XfL = (f16x8*)(ws + (2 << 20) + (size_t)NB * NFRAG * 16);       // 24 MiB
    float* v12 = (float*)(ws + (2 << 20) + (size_t)2 * NB * NFRAG * 16);   // 2.25 MiB
    float* logits = (float*)d_out;

    hipFuncSetAttribute((const void*)prep_all,
                        hipFuncAttributeMaxDynamicSharedMemorySize, SMEM_PREP);
    hipFuncSetAttribute((const void*)ntn_main,
                        hipFuncAttributeMaxDynamicSharedMemorySize, SMEM_MAIN);

    prep_all<<<256 + NB, 256, SMEM_PREP, stream>>>(W, WfH, WfL, texts, XfH, XfL,
                                                   V1w, V1b, V2w, V2b, v12);
    ntn_main<<<NB * NK, 256, SMEM_MAIN, stream>>>(XfH, XfL, WfH, WfL, Wb, v12, Uw, Ub, logits);
    softmax_rows<<<NB * NF / 4, 256, 0, stream>>>(logits);
}